// Round 11
// baseline (359.042 us; speedup 1.0000x reference)
//
#include <hip/hip_runtime.h>
#include <hip/hip_bf16.h>
#include <cstdint>
#include <cstddef>

#define VV 50000
#define HH 1024
#define NROWS 4096
#define VPAD 50176      // padded reordered-W rows
#define SP1 4000
#define SP2 20000
#define SP3 50000

#define BM 128
#define BN 128
#define BK 128
#define NKT (HH / BK)           // 8
#define ROWB 144                // LDS row stride: 128 data + 16 pad (bank rotate)
#define SLOT_A (BM * ROWB)      // 18432 B; dbuf = 36864 B
#define NCHA (SLOT_A / 16)      // 1152 staging chunks per A tile

// reordered-W column map: [0..3999]=weight, [4000..4001]=tail_vectors,
// [4002..50001]=weight[4000..49999], rest zero-pad
#define CB_T1 4002
#define CB_T2 20002
#define CL_HEAD 4002
#define CL_T1 20002
#define CL_T2 50002
#define CT_HEAD 32
#define CT_T1 125
#define CT_T2 235
#define PH_STRIDE 64    // 2*CT_HEAD
#define PT1_STRIDE 250  // 2*CT_T1
#define PT2_STRIDE 470  // 2*CT_T2
#define NRT 32          // row tiles (4096/128)
#define NB2 (NRT * CT_T2)       // 7520
#define NB1 (NRT * CT_T1)       // 4000
#define NBH (NRT * CT_HEAD)     // 1024

#define WSCALE 256.0f
#define HSCALE 16.0f
#define INVSCALE (1.0f / 4096.0f)
#define UNIT_SCALE 0x7f7f7f7fu  // E8M0 1.0 in every byte

typedef __attribute__((ext_vector_type(4))) int i32x4;
typedef __attribute__((ext_vector_type(8))) int i32x8;
typedef __attribute__((ext_vector_type(4))) float f32x4;

typedef __attribute__((address_space(1))) unsigned int uint_g;
typedef __attribute__((address_space(3))) unsigned int uint_l;

__device__ __forceinline__ void gload16(const void* g, void* l) {
  __builtin_amdgcn_global_load_lds((const uint_g*)g, (uint_l*)l, 16, 0, 0);
}

// pack 4 floats -> 4 fp8 e4m3 bytes
__device__ __forceinline__ unsigned int pk4(float a, float b, float c, float d) {
  int p = __builtin_amdgcn_cvt_pk_fp8_f32(a, b, 0, 0);
  p = __builtin_amdgcn_cvt_pk_fp8_f32(c, d, p, 1);
  return (unsigned int)p;
}

// ---- convert weight + tail_vectors -> fp8 (x256), reordered rows ----
__global__ void convW(const float* __restrict__ w, const float* __restrict__ tails,
                      unsigned char* __restrict__ Wf) {
  const size_t nq = (size_t)VPAD * HH / 4;
  for (size_t q = (size_t)blockIdx.x * blockDim.x + threadIdx.x; q < nq;
       q += (size_t)gridDim.x * blockDim.x) {
    const size_t e = q * 4;
    const int row = (int)(e >> 10);
    unsigned int o;
    if (row < 4000) {
      float4 f = *(const float4*)(w + e);
      o = pk4(f.x * WSCALE, f.y * WSCALE, f.z * WSCALE, f.w * WSCALE);
    } else if (row < 4002) {
      float4 f = *(const float4*)(tails + (e - (size_t)4000 * HH));
      o = pk4(f.x * WSCALE, f.y * WSCALE, f.z * WSCALE, f.w * WSCALE);
    } else if (row < 50002) {
      float4 f = *(const float4*)(w + (e - 2048));
      o = pk4(f.x * WSCALE, f.y * WSCALE, f.z * WSCALE, f.w * WSCALE);
    } else {
      o = 0u;
    }
    *(unsigned int*)(Wf + e) = o;
  }
}

// reordered bias (pads get -1e30 so exp() underflows to 0)
__global__ void biasK(const float* __restrict__ bias, const float* __restrict__ tb,
                      float* __restrict__ biasr) {
  const int r = blockIdx.x * 256 + threadIdx.x;
  if (r >= VPAD) return;
  float v;
  if (r < 4000) v = bias[r];
  else if (r == 4000) v = tb[0];
  else if (r == 4001) v = tb[1];
  else if (r < 50002) v = bias[r - 2];
  else v = -1e30f;
  biasr[r] = v;
}

__global__ void convH(const float* __restrict__ h, unsigned char* __restrict__ Hf) {
  const size_t nq = (size_t)NROWS * HH / 4;
  for (size_t q = (size_t)blockIdx.x * blockDim.x + threadIdx.x; q < nq;
       q += (size_t)gridDim.x * blockDim.x) {
    const size_t e = q * 4;
    float4 f = *(const float4*)(h + e);
    *(unsigned int*)(Hf + e) =
        pk4(f.x * HSCALE, f.y * HSCALE, f.z * HSCALE, f.w * HSCALE);
  }
}

// ---- deterministic cluster scan: compact index per row, counts ----
__global__ __launch_bounds__(1024) void scanK(const int* __restrict__ targets,
                                              int* __restrict__ cidx,
                                              int* __restrict__ counts) {
  __shared__ int s1[1024], s2[1024];
  const int tid = threadIdx.x;
  int c[4];
  int n1 = 0, n2 = 0;
#pragma unroll
  for (int j = 0; j < 4; j++) {
    const int t = targets[tid * 4 + j];
    c[j] = (t >= SP1) + (t >= SP2);
    n1 += (c[j] == 1);
    n2 += (c[j] == 2);
  }
  s1[tid] = n1;
  s2[tid] = n2;
  __syncthreads();
  for (int off = 1; off < 1024; off <<= 1) {
    const int a1 = (tid >= off) ? s1[tid - off] : 0;
    const int a2 = (tid >= off) ? s2[tid - off] : 0;
    __syncthreads();
    s1[tid] += a1;
    s2[tid] += a2;
    __syncthreads();
  }
  int e1 = s1[tid] - n1, e2 = s2[tid] - n2;
#pragma unroll
  for (int j = 0; j < 4; j++) {
    if (c[j] == 1) cidx[tid * 4 + j] = e1++;
    else if (c[j] == 2) cidx[tid * 4 + j] = e2++;
    else cidx[tid * 4 + j] = 0;
  }
  if (tid == 1023) {
    counts[0] = s1[1023];
    counts[1] = s2[1023];
    counts[2] = NROWS;
  }
}

// zero both compact-H fp8 buffers (contiguous)
__global__ void zeroHc(uint4* __restrict__ Hc) {
  const size_t n16 = (size_t)2 * NROWS * HH / 16;
  const uint4 z = {0u, 0u, 0u, 0u};
  for (size_t i = (size_t)blockIdx.x * blockDim.x + threadIdx.x; i < n16;
       i += (size_t)gridDim.x * blockDim.x)
    Hc[i] = z;
}

// gather fp8 H rows into per-cluster compact matrices (1 wave per row)
__global__ __launch_bounds__(256) void gatherK(const unsigned char* __restrict__ Hf,
                                               const int* __restrict__ targets,
                                               const int* __restrict__ cidx,
                                               unsigned char* __restrict__ Hc1,
                                               unsigned char* __restrict__ Hc2) {
  const int row = blockIdx.x * 4 + (threadIdx.x >> 6);
  const int lane = threadIdx.x & 63;
  const int t = targets[row];
  const int cl = (t >= SP1) + (t >= SP2);
  if (cl == 0) return;
  unsigned char* dst = (cl == 1 ? Hc1 : Hc2) + (size_t)cidx[row] * HH;
  const unsigned char* src = Hf + (size_t)row * HH;
  *(uint4*)(dst + lane * 16) = *(const uint4*)(src + lane * 16);
}

// ---- fused MX-fp8 GEMM (all 3 segments) + sum-exp epilogue ----
// One dispatch: blocks [0,NB2)=tail2, [NB2,NB2+NB1)=tail1, rest=head.
// Within a segment colTile is fastest (trailing early-exits, XCD balance).
// 256 threads (4 waves 2x2, wave 64x64); BK=128.
// A staged in LDS (double-buffer, 144-B padded rows, gload_lds w/ dup chunk);
// B read DIRECT from global (L2/L3-resident Wf) into regs, distance-1
// prefetch: issue B(t+1) at tile start, register-copy waits after MFMA phase.
// LDS = 36.9 KiB/block. K-loop unroll 1 (full unroll spilled, r7/r8).
__global__ __launch_bounds__(256, 2) void gemm_fused(
    const unsigned char* __restrict__ Hf, const unsigned char* __restrict__ Hc1,
    const unsigned char* __restrict__ Hc2, const unsigned char* __restrict__ Wf,
    const float* __restrict__ biasr, float* __restrict__ ph,
    float* __restrict__ pt1, float* __restrict__ pt2,
    const int* __restrict__ counts) {
  const int bid = blockIdx.x;
  const unsigned char* Ab;
  float* partials;
  int CT, colbase, col_limit, b, Mc;
  if (bid < NB2) {
    b = bid; CT = CT_T2; colbase = CB_T2; col_limit = CL_T2;
    Ab = Hc2; partials = pt2; Mc = counts[1];
  } else if (bid < NB2 + NB1) {
    b = bid - NB2; CT = CT_T1; colbase = CB_T1; col_limit = CL_T1;
    Ab = Hc1; partials = pt1; Mc = counts[0];
  } else {
    b = bid - NB2 - NB1; CT = CT_HEAD; colbase = 0; col_limit = CL_HEAD;
    Ab = Hf; partials = ph; Mc = NROWS;
  }
  const int rowTile = b / CT;
  const int colTile = b - rowTile * CT;
  if (rowTile * BM >= Mc) return;

  __shared__ __align__(16) unsigned char lds[2 * SLOT_A];  // 36864 B

  const int tid = threadIdx.x;
  const int w = tid >> 6, lane = tid & 63;
  const int wr = w >> 1, wc = w & 1;
  const int fr = lane & 15, fq = lane >> 4;
  const unsigned char* Ag = Ab + (size_t)rowTile * BM * HH;
  const unsigned char* Bg = Wf + (size_t)(colbase + colTile * BN) * HH;

  // A staging: 1152 chunks (128 rows x 9; chunk j==8 stages a dup into pad)
  int srcOffA[5];
  bool valA[5];
#pragma unroll
  for (int i = 0; i < 5; i++) {
    const int c = i * 256 + tid;
    valA[i] = (c < NCHA);  // wave-uniform (i=4: waves 0,1 only)
    const int row = c / 9, j = c - row * 9;
    const int jb = (j < 8) ? j * 16 : 0;
    srcOffA[i] = row * HH + jb;
  }

  // A fragment read offsets (bytes within slot)
  int offA[4];
#pragma unroll
  for (int mi = 0; mi < 4; mi++) {
    const int R = wr * 64 + mi * 16 + fr;
    offA[mi] = R * ROWB + fq * 32;
  }

  // B direct-load base pointers (per ni frag): 32 contiguous K bytes per lane
  const unsigned char* bptr[4];
#pragma unroll
  for (int ni = 0; ni < 4; ni++) {
    const int col = wc * 64 + ni * 16 + fr;
    bptr[ni] = Bg + (size_t)col * HH + fq * 32;
  }

  f32x4 acc[4][4];
#pragma unroll
  for (int i = 0; i < 4; i++)
#pragma unroll
    for (int j = 0; j < 4; j++) acc[i][j] = (f32x4){0.f, 0.f, 0.f, 0.f};

  auto STAGE = [&](int t) {
    unsigned char* base = lds + (t & 1) * SLOT_A;
    const int k0 = t * BK;
#pragma unroll
    for (int i = 0; i < 5; i++)
      if (valA[i]) gload16(Ag + (size_t)srcOffA[i] + k0, base + (i * 256 + tid) * 16);
  };

  // prologue: B(0) -> bc, A(0) -> LDS slot 0
  i32x4 bc_lo[4], bc_hi[4], bn_lo[4], bn_hi[4];
#pragma unroll
  for (int ni = 0; ni < 4; ni++) {
    bc_lo[ni] = *(const i32x4*)(bptr[ni]);
    bc_hi[ni] = *(const i32x4*)(bptr[ni] + 16);
  }
  STAGE(0);

#pragma unroll 1
  for (int t = 0; t < NKT; ++t) {
    if (t + 1 < NKT) {
      const int koff = (t + 1) * BK;
#pragma unroll
      for (int ni = 0; ni < 4; ni++) {
        bn_lo[ni] = *(const i32x4*)(bptr[ni] + koff);
        bn_hi[ni] = *(const i32x4*)(bptr[ni] + koff + 16);
      }
      STAGE(t + 1);
      asm volatile("s_waitcnt vmcnt(12)" ::: "memory");  // drain A(t)
    } else {
      asm volatile("s_waitcnt vmcnt(0)" ::: "memory");
    }
    __builtin_amdgcn_s_barrier();

    const unsigned char* sl = lds + (t & 1) * SLOT_A;
    __builtin_amdgcn_s_setprio(1);
#pragma unroll
    for (int mi = 0; mi < 4; mi++) {
      i32x4 lo = *(const i32x4*)(sl + offA[mi]);
      i32x4 hi = *(const i32x4*)(sl + offA[mi] + 16);
      i32x8 a8 = __builtin_shufflevector(lo, hi, 0, 1, 2, 3, 4, 5, 6, 7);
#pragma unroll
      for (int ni = 0; ni < 4; ni++) {
        i32x8 b8 = __builtin_shufflevector(bc_lo[ni], bc_hi[ni], 0, 1, 2, 3, 4, 5, 6, 7);
        acc[mi][ni] = __builtin_amdgcn_mfma_scale_f32_16x16x128_f8f6f4(
            a8, b8, acc[mi][ni], 0, 0, 0, UNIT_SCALE, 0, UNIT_SCALE);
      }
    }
    __builtin_amdgcn_s_setprio(0);
    if (t + 1 < NKT) {
      // consume-wait for B(t+1) lands here (after MFMA phase)
#pragma unroll
      for (int ni = 0; ni < 4; ni++) {
        bc_lo[ni] = bn_lo[ni];
        bc_hi[ni] = bn_hi[ni];
      }
    }
    __builtin_amdgcn_s_barrier();
  }

  // ---- epilogue: per-(row, 64-col chunk) sum of exp(logit/4096 + bias) ----
  const int colw = colTile * BN + wc * 64;
  float biasv[4];
#pragma unroll
  for (int ni = 0; ni < 4; ni++) {
    const int gcol = colbase + colw + ni * 16 + fr;
    biasv[ni] = (gcol < col_limit) ? biasr[gcol] : -1e30f;
  }
  const int chunk = colTile * 2 + wc;
  const int pstride = CT * 2;

#pragma unroll
  for (int mi = 0; mi < 4; mi++) {
    const int rowg = rowTile * BM + wr * 64 + mi * 16 + fq * 4;
#pragma unroll
    for (int r = 0; r < 4; r++) {
      float p = 0.f;
#pragma unroll
      for (int ni = 0; ni < 4; ni++)
        p += __expf(acc[mi][ni][r] * INVSCALE + biasv[ni]);
#pragma unroll
      for (int m = 1; m < 16; m <<= 1) p += __shfl_xor(p, m);
      if (fr == 0) partials[(size_t)(rowg + r) * pstride + chunk] = p;
    }
  }
}

// ---- per-row: combine chunk partials, selected logits in fp32, loss ----
__global__ __launch_bounds__(256) void rowloss(
    const float* __restrict__ ph, const float* __restrict__ pt1,
    const float* __restrict__ pt2, const int* __restrict__ cidx,
    const float* __restrict__ hiddens, const float* __restrict__ weight,
    const float* __restrict__ bias, const float* __restrict__ tails,
    const float* __restrict__ tail_bias, const int* __restrict__ targets,
    float* __restrict__ losses) {
  const int row = blockIdx.x * 4 + (threadIdx.x >> 6);
  const int lane = threadIdx.x & 63;
  const int t = targets[row];
  const int cl = (t >= SP1) + (t >= SP2);

  float s0 = ph[(size_t)row * PH_STRIDE + lane];  // exactly 64 chunks
  float st = 0.f;
  if (cl == 1) {
    const float* P = pt1 + (size_t)cidx[row] * PT1_STRIDE;
    for (int c = lane; c < PT1_STRIDE; c += 64) st += P[c];
  } else if (cl == 2) {
    const float* P = pt2 + (size_t)cidx[row] * PT2_STRIDE;
    for (int c = lane; c < PT2_STRIDE; c += 64) st += P[c];
  }
#pragma unroll
  for (int m = 1; m < 64; m <<= 1) {
    s0 += __shfl_xor(s0, m);
    st += __shfl_xor(st, m);
  }

  const float* hv = hiddens + (size_t)row * HH;
  const float* w1;
  float b1;
  if (cl == 0) {
    w1 = weight + (size_t)t * HH;
    b1 = bias[t];
  } else if (cl == 1) {
    w1 = tails + HH;  // head col 4001 <-> tail_vectors[1]
    b1 = tail_bias[1];
  } else {
    w1 = tails;       // head col 4000 <-> tail_vectors[0]
    b1 = tail_bias[0];
  }
  float d1 = 0.f, d2 = 0.f;
  for (int i = lane; i < HH; i += 64) d1 += hv[i] * w1[i];
  if (cl > 0) {
    const float* w2 = weight + (size_t)t * HH;
    for (int i = lane; i < HH; i += 64) d2 += hv[i] * w2[i];
  }
#pragma unroll
  for (int m = 1; m < 64; m <<= 1) {
    d1 += __shfl_xor(d1, m);
    d2 += __shfl_xor(d2, m);
  }
  if (lane == 0) {
    float loss = logf(s0) - (d1 + b1);
    if (cl > 0) loss += logf(st) - (d2 + bias[t]);
    losses[row] = loss;
  }
}

__global__ void meanloss(const float* __restrict__ losses, float* __restrict__ out) {
  __shared__ float red[256];
  float s = 0.f;
  for (int i = threadIdx.x; i < NROWS; i += 256) s += losses[i];
  red[threadIdx.x] = s;
  __syncthreads();
  for (int st = 128; st > 0; st >>= 1) {
    if ((int)threadIdx.x < st) red[threadIdx.x] += red[threadIdx.x + st];
    __syncthreads();
  }
  if (threadIdx.x == 0) out[0] = red[0] / (float)NROWS;
}

extern "C" void kernel_launch(void* const* d_in, const int* in_sizes, int n_in,
                              void* d_out, int out_size, void* d_ws, size_t ws_size,
                              hipStream_t stream) {
  const float* weight = (const float*)d_in[0];
  const float* bias = (const float*)d_in[1];
  const float* hiddens = (const float*)d_in[2];
  const float* tails = (const float*)d_in[3];
  const float* tail_bias = (const float*)d_in[4];
  const int* targets = (const int*)d_in[5];
  float* out = (float*)d_out;

  char* ws = (char*)d_ws;
  unsigned char* Wf = (unsigned char*)ws;                      // 50176*1024 = 51,380,224
  unsigned char* Hf = (unsigned char*)(ws + 51380224);         //  4,194,304
  unsigned char* Hc1 = (unsigned char*)(ws + 55574528);        //  4,194,304
  unsigned char* Hc2 = (unsigned char*)(ws + 59768832);        //  4,194,304 (contig w/ Hc1)
  float* ph = (float*)(ws + 63963136);                         //  4096*64*4  = 1,048,576
  float* pt1 = (float*)(ws + 65011712);                        //  4096*250*4 = 4,096,000
  float* pt2 = (float*)(ws + 69107712);                        //  4096*470*4 = 7,700,480
  float* biasr = (float*)(ws + 76808192);                      //  50176*4    = 200,704
  int* cidx = (int*)(ws + 77008896);                           //  16,384
  int* counts = (int*)(ws + 77025280);                         //  64
  float* losses = (float*)(ws + 77025344);                     //  16,384

  hipLaunchKernelGGL(convW, dim3(2048), dim3(256), 0, stream, weight, tails, Wf);
  hipLaunchKernelGGL(biasK, dim3((VPAD + 255) / 256), dim3(256), 0, stream, bias,
                     tail_bias, biasr);
  hipLaunchKernelGGL(convH, dim3(512), dim3(256), 0, stream, hiddens, Hf);
  hipLaunchKernelGGL(scanK, dim3(1), dim3(1024), 0, stream, targets, cidx, counts);
  hipLaunchKernelGGL(zeroHc, dim3(1024), dim3(256), 0, stream, (uint4*)Hc1);
  hipLaunchKernelGGL(gatherK, dim3(NROWS / 4), dim3(256), 0, stream, Hf, targets, cidx,
                     Hc1, Hc2);
  // fused: tail2 blocks [0,7520), tail1 [7520,11520), head [11520,12544)
  hipLaunchKernelGGL(gemm_fused, dim3(NB2 + NB1 + NBH), dim3(256), 0, stream, Hf, Hc1,
                     Hc2, Wf, biasr, ph, pt1, pt2, counts);
  hipLaunchKernelGGL(rowloss, dim3(NROWS / 4), dim3(256), 0, stream, ph, pt1, pt2, cidx,
                     hiddens, weight, bias, tails, tail_bias, targets, losses);
  hipLaunchKernelGGL(meanloss, dim3(1), dim3(256), 0, stream, losses, out);
}

// Round 12
// 264.882 us; speedup vs baseline: 1.3555x; 1.3555x over previous
//
#include <hip/hip_runtime.h>
#include <hip/hip_bf16.h>
#include <cstdint>
#include <cstddef>

#define VV 50000
#define HH 1024
#define NROWS 4096
#define VPAD 50176      // padded reordered-W rows
#define SP1 4000
#define SP2 20000
#define SP3 50000

#define BM 128
#define BN 128
#define BK 128
#define NKT (HH / BK)           // 8
#define ROWB 144                // LDS row stride: 128 data + 16 pad (bank rotate)
#define A_SLOT_B (BM * ROWB)    // 18432
#define SLOT_B (2 * A_SLOT_B)   // 36864 B/slot (A+B); dbuf = 73728 -> 2 blocks/CU
#define NCH (SLOT_B / 16)       // 2304 chunks per tile
#define LPT (NCH / 256)         // 9 loads per thread per tile

// reordered-W column map: [0..3999]=weight, [4000..4001]=tail_vectors,
// [4002..50001]=weight[4000..49999], rest zero-pad
#define CB_T1 4002
#define CB_T2 20002
#define CL_HEAD 4002
#define CL_T1 20002
#define CL_T2 50002
#define CT_HEAD 32
#define CT_T1 125
#define CT_T2 235
#define PH_STRIDE 64    // 2*CT_HEAD
#define PT1_STRIDE 250  // 2*CT_T1
#define PT2_STRIDE 470  // 2*CT_T2
#define NRT 32          // row tiles (4096/128)
#define NB2 (NRT * CT_T2)       // 7520
#define NB1 (NRT * CT_T1)       // 4000
#define NBH (NRT * CT_HEAD)     // 1024

#define WSCALE 256.0f
#define HSCALE 16.0f
#define INVSCALE (1.0f / 4096.0f)
#define UNIT_SCALE 0x7f7f7f7fu  // E8M0 1.0 in every byte

typedef __attribute__((ext_vector_type(4))) int i32x4;
typedef __attribute__((ext_vector_type(8))) int i32x8;
typedef __attribute__((ext_vector_type(4))) float f32x4;

typedef __attribute__((address_space(1))) unsigned int uint_g;
typedef __attribute__((address_space(3))) unsigned int uint_l;

__device__ __forceinline__ void gload16(const void* g, void* l) {
  __builtin_amdgcn_global_load_lds((const uint_g*)g, (uint_l*)l, 16, 0, 0);
}

// pack 4 floats -> 4 fp8 e4m3 bytes
__device__ __forceinline__ unsigned int pk4(float a, float b, float c, float d) {
  int p = __builtin_amdgcn_cvt_pk_fp8_f32(a, b, 0, 0);
  p = __builtin_amdgcn_cvt_pk_fp8_f32(c, d, p, 1);
  return (unsigned int)p;
}

// ---- convert weight + tail_vectors -> fp8 (x256), reordered rows ----
__global__ void convW(const float* __restrict__ w, const float* __restrict__ tails,
                      unsigned char* __restrict__ Wf) {
  const size_t nq = (size_t)VPAD * HH / 4;
  for (size_t q = (size_t)blockIdx.x * blockDim.x + threadIdx.x; q < nq;
       q += (size_t)gridDim.x * blockDim.x) {
    const size_t e = q * 4;
    const int row = (int)(e >> 10);
    unsigned int o;
    if (row < 4000) {
      float4 f = *(const float4*)(w + e);
      o = pk4(f.x * WSCALE, f.y * WSCALE, f.z * WSCALE, f.w * WSCALE);
    } else if (row < 4002) {
      float4 f = *(const float4*)(tails + (e - (size_t)4000 * HH));
      o = pk4(f.x * WSCALE, f.y * WSCALE, f.z * WSCALE, f.w * WSCALE);
    } else if (row < 50002) {
      float4 f = *(const float4*)(w + (e - 2048));
      o = pk4(f.x * WSCALE, f.y * WSCALE, f.z * WSCALE, f.w * WSCALE);
    } else {
      o = 0u;
    }
    *(unsigned int*)(Wf + e) = o;
  }
}

// reordered bias (pads get -1e30 so exp() underflows to 0)
__global__ void biasK(const float* __restrict__ bias, const float* __restrict__ tb,
                      float* __restrict__ biasr) {
  const int r = blockIdx.x * 256 + threadIdx.x;
  if (r >= VPAD) return;
  float v;
  if (r < 4000) v = bias[r];
  else if (r == 4000) v = tb[0];
  else if (r == 4001) v = tb[1];
  else if (r < 50002) v = bias[r - 2];
  else v = -1e30f;
  biasr[r] = v;
}

__global__ void convH(const float* __restrict__ h, unsigned char* __restrict__ Hf) {
  const size_t nq = (size_t)NROWS * HH / 4;
  for (size_t q = (size_t)blockIdx.x * blockDim.x + threadIdx.x; q < nq;
       q += (size_t)gridDim.x * blockDim.x) {
    const size_t e = q * 4;
    float4 f = *(const float4*)(h + e);
    *(unsigned int*)(Hf + e) =
        pk4(f.x * HSCALE, f.y * HSCALE, f.z * HSCALE, f.w * HSCALE);
  }
}

// ---- deterministic cluster scan: compact index per row, counts ----
__global__ __launch_bounds__(1024) void scanK(const int* __restrict__ targets,
                                              int* __restrict__ cidx,
                                              int* __restrict__ counts) {
  __shared__ int s1[1024], s2[1024];
  const int tid = threadIdx.x;
  int c[4];
  int n1 = 0, n2 = 0;
#pragma unroll
  for (int j = 0; j < 4; j++) {
    const int t = targets[tid * 4 + j];
    c[j] = (t >= SP1) + (t >= SP2);
    n1 += (c[j] == 1);
    n2 += (c[j] == 2);
  }
  s1[tid] = n1;
  s2[tid] = n2;
  __syncthreads();
  for (int off = 1; off < 1024; off <<= 1) {
    const int a1 = (tid >= off) ? s1[tid - off] : 0;
    const int a2 = (tid >= off) ? s2[tid - off] : 0;
    __syncthreads();
    s1[tid] += a1;
    s2[tid] += a2;
    __syncthreads();
  }
  int e1 = s1[tid] - n1, e2 = s2[tid] - n2;
#pragma unroll
  for (int j = 0; j < 4; j++) {
    if (c[j] == 1) cidx[tid * 4 + j] = e1++;
    else if (c[j] == 2) cidx[tid * 4 + j] = e2++;
    else cidx[tid * 4 + j] = 0;
  }
  if (tid == 1023) {
    counts[0] = s1[1023];
    counts[1] = s2[1023];
    counts[2] = NROWS;
  }
}

// zero both compact-H fp8 buffers (contiguous)
__global__ void zeroHc(uint4* __restrict__ Hc) {
  const size_t n16 = (size_t)2 * NROWS * HH / 16;
  const uint4 z = {0u, 0u, 0u, 0u};
  for (size_t i = (size_t)blockIdx.x * blockDim.x + threadIdx.x; i < n16;
       i += (size_t)gridDim.x * blockDim.x)
    Hc[i] = z;
}

// gather fp8 H rows into per-cluster compact matrices (1 wave per row)
__global__ __launch_bounds__(256) void gatherK(const unsigned char* __restrict__ Hf,
                                               const int* __restrict__ targets,
                                               const int* __restrict__ cidx,
                                               unsigned char* __restrict__ Hc1,
                                               unsigned char* __restrict__ Hc2) {
  const int row = blockIdx.x * 4 + (threadIdx.x >> 6);
  const int lane = threadIdx.x & 63;
  const int t = targets[row];
  const int cl = (t >= SP1) + (t >= SP2);
  if (cl == 0) return;
  unsigned char* dst = (cl == 1 ? Hc1 : Hc2) + (size_t)cidx[row] * HH;
  const unsigned char* src = Hf + (size_t)row * HH;
  *(uint4*)(dst + lane * 16) = *(const uint4*)(src + lane * 16);
}

// ---- fused MX-fp8 GEMM (all 3 segments) + sum-exp epilogue ----
// One dispatch: blocks [0,NB2)=tail2, [NB2,NB2+NB1)=tail1, rest=head.
// Within a segment colTile is fastest (trailing early-exits, XCD balance).
// GEMM body = round-10 proven structure: 256 threads (4 waves 2x2, wave
// 64x64), BK=128, A+B staged in LDS via gload_lds (144-B padded rows, dup
// chunk), double-buffer 72 KiB -> 2 blocks/CU, counted vmcnt(9), unroll 1.
__global__ __launch_bounds__(256, 2) void gemm_fused(
    const unsigned char* __restrict__ Hf, const unsigned char* __restrict__ Hc1,
    const unsigned char* __restrict__ Hc2, const unsigned char* __restrict__ Wf,
    const float* __restrict__ biasr, float* __restrict__ ph,
    float* __restrict__ pt1, float* __restrict__ pt2,
    const int* __restrict__ counts) {
  const int bid = blockIdx.x;
  const unsigned char* Ab;
  float* partials;
  int CT, colbase, col_limit, b, Mc;
  if (bid < NB2) {
    b = bid; CT = CT_T2; colbase = CB_T2; col_limit = CL_T2;
    Ab = Hc2; partials = pt2; Mc = counts[1];
  } else if (bid < NB2 + NB1) {
    b = bid - NB2; CT = CT_T1; colbase = CB_T1; col_limit = CL_T1;
    Ab = Hc1; partials = pt1; Mc = counts[0];
  } else {
    b = bid - NB2 - NB1; CT = CT_HEAD; colbase = 0; col_limit = CL_HEAD;
    Ab = Hf; partials = ph; Mc = NROWS;
  }
  const int rowTile = b / CT;
  const int colTile = b - rowTile * CT;
  if (rowTile * BM >= Mc) return;

  __shared__ __align__(16) unsigned char lds[2 * SLOT_B];  // 73728 B

  const int tid = threadIdx.x;
  const int w = tid >> 6, lane = tid & 63;
  const int wr = w >> 1, wc = w & 1;
  const int fr = lane & 15, fq = lane >> 4;
  const unsigned char* Ag = Ab + (size_t)rowTile * BM * HH;
  const unsigned char* Bg = Wf + (size_t)(colbase + colTile * BN) * HH;

  // staging: chunk c (16B) -> dest byte c*16; source precomputed per i.
  // A: c in [0,1152): row=c/9, j=c%9 ; B: c-1152 likewise. j==8 -> dup of j=0.
  const unsigned char* srcPtr[LPT];
#pragma unroll
  for (int i = 0; i < LPT; i++) {
    const int c = i * 256 + tid;
    const bool isA = c < NCH / 2;
    const int cc = isA ? c : c - NCH / 2;
    const int row = cc / 9;
    const int j = cc - row * 9;
    const int jb = (j < 8) ? j * 16 : 0;
    srcPtr[i] = (isA ? Ag : Bg) + (size_t)row * HH + jb;
  }

  // fragment read offsets (bytes within slot); hi half at +16 (contiguous)
  int offA[4], offB[4];
#pragma unroll
  for (int mi = 0; mi < 4; mi++) {
    const int R = wr * 64 + mi * 16 + fr;
    offA[mi] = R * ROWB + fq * 32;
  }
#pragma unroll
  for (int ni = 0; ni < 4; ni++) {
    const int R = wc * 64 + ni * 16 + fr;
    offB[ni] = A_SLOT_B + R * ROWB + fq * 32;
  }

  f32x4 acc[4][4];
#pragma unroll
  for (int i = 0; i < 4; i++)
#pragma unroll
    for (int j = 0; j < 4; j++) acc[i][j] = (f32x4){0.f, 0.f, 0.f, 0.f};

  auto STAGE = [&](int t) {
    unsigned char* base = lds + (t & 1) * SLOT_B;
    const int k0 = t * BK;  // byte offset (1 B/elem)
#pragma unroll
    for (int i = 0; i < LPT; i++)
      gload16(srcPtr[i] + k0, base + (i * 256 + tid) * 16);
  };

  STAGE(0);

#pragma unroll 1
  for (int t = 0; t < NKT; ++t) {
    if (t + 1 < NKT) {
      STAGE(t + 1);
      asm volatile("s_waitcnt vmcnt(9)" ::: "memory");
    } else {
      asm volatile("s_waitcnt vmcnt(0)" ::: "memory");
    }
    __builtin_amdgcn_s_barrier();

    const unsigned char* sl = lds + (t & 1) * SLOT_B;
    // B fragments for the whole tile (32 VGPR)
    i32x8 b8[4];
#pragma unroll
    for (int ni = 0; ni < 4; ni++) {
      i32x4 lo = *(const i32x4*)(sl + offB[ni]);
      i32x4 hi = *(const i32x4*)(sl + offB[ni] + 16);
      b8[ni] = __builtin_shufflevector(lo, hi, 0, 1, 2, 3, 4, 5, 6, 7);
    }
    __builtin_amdgcn_s_setprio(1);
#pragma unroll
    for (int mi = 0; mi < 4; mi++) {
      i32x4 lo = *(const i32x4*)(sl + offA[mi]);
      i32x4 hi = *(const i32x4*)(sl + offA[mi] + 16);
      i32x8 a8 = __builtin_shufflevector(lo, hi, 0, 1, 2, 3, 4, 5, 6, 7);
#pragma unroll
      for (int ni = 0; ni < 4; ni++)
        acc[mi][ni] = __builtin_amdgcn_mfma_scale_f32_16x16x128_f8f6f4(
            a8, b8[ni], acc[mi][ni], 0, 0, 0, UNIT_SCALE, 0, UNIT_SCALE);
    }
    __builtin_amdgcn_s_setprio(0);
    __builtin_amdgcn_s_barrier();
  }

  // ---- epilogue: per-(row, 64-col chunk) sum of exp(logit/4096 + bias) ----
  const int colw = colTile * BN + wc * 64;
  float biasv[4];
#pragma unroll
  for (int ni = 0; ni < 4; ni++) {
    const int gcol = colbase + colw + ni * 16 + fr;
    biasv[ni] = (gcol < col_limit) ? biasr[gcol] : -1e30f;
  }
  const int chunk = colTile * 2 + wc;
  const int pstride = CT * 2;

#pragma unroll
  for (int mi = 0; mi < 4; mi++) {
    const int rowg = rowTile * BM + wr * 64 + mi * 16 + fq * 4;
#pragma unroll
    for (int r = 0; r < 4; r++) {
      float p = 0.f;
#pragma unroll
      for (int ni = 0; ni < 4; ni++)
        p += __expf(acc[mi][ni][r] * INVSCALE + biasv[ni]);
#pragma unroll
      for (int m = 1; m < 16; m <<= 1) p += __shfl_xor(p, m);
      if (fr == 0) partials[(size_t)(rowg + r) * pstride + chunk] = p;
    }
  }
}

// ---- per-row: combine chunk partials, selected logits in fp32, loss ----
__global__ __launch_bounds__(256) void rowloss(
    const float* __restrict__ ph, const float* __restrict__ pt1,
    const float* __restrict__ pt2, const int* __restrict__ cidx,
    const float* __restrict__ hiddens, const float* __restrict__ weight,
    const float* __restrict__ bias, const float* __restrict__ tails,
    const float* __restrict__ tail_bias, const int* __restrict__ targets,
    float* __restrict__ losses) {
  const int row = blockIdx.x * 4 + (threadIdx.x >> 6);
  const int lane = threadIdx.x & 63;
  const int t = targets[row];
  const int cl = (t >= SP1) + (t >= SP2);

  float s0 = ph[(size_t)row * PH_STRIDE + lane];  // exactly 64 chunks
  float st = 0.f;
  if (cl == 1) {
    const float* P = pt1 + (size_t)cidx[row] * PT1_STRIDE;
    for (int c = lane; c < PT1_STRIDE; c += 64) st += P[c];
  } else if (cl == 2) {
    const float* P = pt2 + (size_t)cidx[row] * PT2_STRIDE;
    for (int c = lane; c < PT2_STRIDE; c += 64) st += P[c];
  }
#pragma unroll
  for (int m = 1; m < 64; m <<= 1) {
    s0 += __shfl_xor(s0, m);
    st += __shfl_xor(st, m);
  }

  const float* hv = hiddens + (size_t)row * HH;
  const float* w1;
  float b1;
  if (cl == 0) {
    w1 = weight + (size_t)t * HH;
    b1 = bias[t];
  } else if (cl == 1) {
    w1 = tails + HH;  // head col 4001 <-> tail_vectors[1]
    b1 = tail_bias[1];
  } else {
    w1 = tails;       // head col 4000 <-> tail_vectors[0]
    b1 = tail_bias[0];
  }
  float d1 = 0.f, d2 = 0.f;
  for (int i = lane; i < HH; i += 64) d1 += hv[i] * w1[i];
  if (cl > 0) {
    const float* w2 = weight + (size_t)t * HH;
    for (int i = lane; i < HH; i += 64) d2 += hv[i] * w2[i];
  }
#pragma unroll
  for (int m = 1; m < 64; m <<= 1) {
    d1 += __shfl_xor(d1, m);
    d2 += __shfl_xor(d2, m);
  }
  if (lane == 0) {
    float loss = logf(s0) - (d1 + b1);
    if (cl > 0) loss += logf(st) - (d2 + bias[t]);
    losses[row] = loss;
  }
}

__global__ void meanloss(const float* __restrict__ losses, float* __restrict__ out) {
  __shared__ float red[256];
  float s = 0.f;
  for (int i = threadIdx.x; i < NROWS; i += 256) s += losses[i];
  red[threadIdx.x] = s;
  __syncthreads();
  for (int st = 128; st > 0; st >>= 1) {
    if ((int)threadIdx.x < st) red[threadIdx.x] += red[threadIdx.x + st];
    __syncthreads();
  }
  if (threadIdx.x == 0) out[0] = red[0] / (float)NROWS;
}

extern "C" void kernel_launch(void* const* d_in, const int* in_sizes, int n_in,
                              void* d_out, int out_size, void* d_ws, size_t ws_size,
                              hipStream_t stream) {
  const float* weight = (const float*)d_in[0];
  const float* bias = (const float*)d_in[1];
  const float* hiddens = (const float*)d_in[2];
  const float* tails = (const float*)d_in[3];
  const float* tail_bias = (const float*)d_in[4];
  const int* targets = (const int*)d_in[5];
  float* out = (float*)d_out;

  char* ws = (char*)d_ws;
  unsigned char* Wf = (unsigned char*)ws;                      // 50176*1024 = 51,380,224
  unsigned char* Hf = (unsigned char*)(ws + 51380224);         //  4,194,304
  unsigned char* Hc1 = (unsigned char*)(ws + 55574528);        //  4,194,304
  unsigned char* Hc2 = (unsigned char*)(ws + 59768832);        //  4,194,304 (contig w/ Hc1)
  float* ph = (float*)(ws + 63963136);                         //  4096*64*4  = 1,048,576
  float* pt1 = (float*)(ws + 65011712);                        //  4096*250*4 = 4,096,000
  float* pt2 = (float*)(ws + 69107712);                        //  4096*470*4 = 7,700,480
  float* biasr = (float*)(ws + 76808192);                      //  50176*4    = 200,704
  int* cidx = (int*)(ws + 77008896);                           //  16,384
  int* counts = (int*)(ws + 77025280);                         //  64
  float* losses = (float*)(ws + 77025344);                     //  16,384

  hipLaunchKernelGGL(convW, dim3(2048), dim3(256), 0, stream, weight, tails, Wf);
  hipLaunchKernelGGL(biasK, dim3((VPAD + 255) / 256), dim3(256), 0, stream, bias,
                     tail_bias, biasr);
  hipLaunchKernelGGL(convH, dim3(512), dim3(256), 0, stream, hiddens, Hf);
  hipLaunchKernelGGL(scanK, dim3(1), dim3(1024), 0, stream, targets, cidx, counts);
  hipLaunchKernelGGL(zeroHc, dim3(1024), dim3(256), 0, stream, (uint4*)Hc1);
  hipLaunchKernelGGL(gatherK, dim3(NROWS / 4), dim3(256), 0, stream, Hf, targets, cidx,
                     Hc1, Hc2);
  // fused: tail2 blocks [0,7520), tail1 [7520,11520), head [11520,12544)
  hipLaunchKernelGGL(gemm_fused, dim3(NB2 + NB1 + NBH), dim3(256), 0, stream, Hf, Hc1,
                     Hc2, Wf, biasr, ph, pt1, pt2, counts);
  hipLaunchKernelGGL(rowloss, dim3(NROWS / 4), dim3(256), 0, stream, ph, pt1, pt2, cidx,
                     hiddens, weight, bias, tails, tail_bias, targets, losses);
  hipLaunchKernelGGL(meanloss, dim3(1), dim3(256), 0, stream, losses, out);
}

// Round 13
// 257.466 us; speedup vs baseline: 1.3945x; 1.0288x over previous
//
#include <hip/hip_runtime.h>
#include <hip/hip_bf16.h>
#include <cstdint>
#include <cstddef>

#define VV 50000
#define HH 1024
#define NROWS 4096
#define VPAD 50432      // padded reordered-W rows (covers 20002+118*256=50210)
#define SP1 4000
#define SP2 20000
#define SP3 50000

#define BM 256
#define BN 256
#define BK 128
#define NKT (HH / BK)           // 8
#define ROWB 144                // LDS row stride: 128 data + 16 pad
#define A_SLOT_B (BM * ROWB)    // 36864
#define SLOT_B (2 * A_SLOT_B)   // 73728 B/slot (A rows then B rows); dbuf 147456
#define NCH (SLOT_B / 16)       // 4608 chunks per tile
#define LPT (NCH / 512)         // 9 loads per thread per tile

// reordered-W column map: [0..3999]=weight, [4000..4001]=tail_vectors,
// [4002..50001]=weight[4000..49999], rest zero-pad
#define CB_T1 4002
#define CB_T2 20002
#define CL_HEAD 4002
#define CL_T1 20002
#define CL_T2 50002
#define CT_HEAD 16
#define CT_T1 63
#define CT_T2 118
#define PH_STRIDE 32    // 2*CT_HEAD
#define PT1_STRIDE 126  // 2*CT_T1
#define PT2_STRIDE 236  // 2*CT_T2
#define NRT 16          // row tiles (4096/256)
#define NB2 (NRT * CT_T2)       // 1888
#define NB1 (NRT * CT_T1)       // 1008
#define NBH (NRT * CT_HEAD)     // 256

#define WSCALE 256.0f
#define HSCALE 16.0f
#define INVSCALE (1.0f / 4096.0f)
#define UNIT_SCALE 0x7f7f7f7fu  // E8M0 1.0 in every byte

typedef __attribute__((ext_vector_type(4))) int i32x4;
typedef __attribute__((ext_vector_type(8))) int i32x8;
typedef __attribute__((ext_vector_type(4))) float f32x4;

typedef __attribute__((address_space(1))) unsigned int uint_g;
typedef __attribute__((address_space(3))) unsigned int uint_l;

__device__ __forceinline__ void gload16(const void* g, void* l) {
  __builtin_amdgcn_global_load_lds((const uint_g*)g, (uint_l*)l, 16, 0, 0);
}

// pack 4 floats -> 4 fp8 e4m3 bytes
__device__ __forceinline__ unsigned int pk4(float a, float b, float c, float d) {
  int p = __builtin_amdgcn_cvt_pk_fp8_f32(a, b, 0, 0);
  p = __builtin_amdgcn_cvt_pk_fp8_f32(c, d, p, 1);
  return (unsigned int)p;
}

// ---- convert weight + tail_vectors -> fp8 (x256), reordered rows ----
__global__ void convW(const float* __restrict__ w, const float* __restrict__ tails,
                      unsigned char* __restrict__ Wf) {
  const size_t nq = (size_t)VPAD * HH / 4;
  for (size_t q = (size_t)blockIdx.x * blockDim.x + threadIdx.x; q < nq;
       q += (size_t)gridDim.x * blockDim.x) {
    const size_t e = q * 4;
    const int row = (int)(e >> 10);
    unsigned int o;
    if (row < 4000) {
      float4 f = *(const float4*)(w + e);
      o = pk4(f.x * WSCALE, f.y * WSCALE, f.z * WSCALE, f.w * WSCALE);
    } else if (row < 4002) {
      float4 f = *(const float4*)(tails + (e - (size_t)4000 * HH));
      o = pk4(f.x * WSCALE, f.y * WSCALE, f.z * WSCALE, f.w * WSCALE);
    } else if (row < 50002) {
      float4 f = *(const float4*)(w + (e - 2048));
      o = pk4(f.x * WSCALE, f.y * WSCALE, f.z * WSCALE, f.w * WSCALE);
    } else {
      o = 0u;
    }
    *(unsigned int*)(Wf + e) = o;
  }
}

// reordered bias (pads get -1e30 so exp() underflows to 0)
__global__ void biasK(const float* __restrict__ bias, const float* __restrict__ tb,
                      float* __restrict__ biasr) {
  const int r = blockIdx.x * 256 + threadIdx.x;
  if (r >= VPAD) return;
  float v;
  if (r < 4000) v = bias[r];
  else if (r == 4000) v = tb[0];
  else if (r == 4001) v = tb[1];
  else if (r < 50002) v = bias[r - 2];
  else v = -1e30f;
  biasr[r] = v;
}

__global__ void convH(const float* __restrict__ h, unsigned char* __restrict__ Hf) {
  const size_t nq = (size_t)NROWS * HH / 4;
  for (size_t q = (size_t)blockIdx.x * blockDim.x + threadIdx.x; q < nq;
       q += (size_t)gridDim.x * blockDim.x) {
    const size_t e = q * 4;
    float4 f = *(const float4*)(h + e);
    *(unsigned int*)(Hf + e) =
        pk4(f.x * HSCALE, f.y * HSCALE, f.z * HSCALE, f.w * HSCALE);
  }
}

// ---- deterministic cluster scan: compact index per row, counts ----
__global__ __launch_bounds__(1024) void scanK(const int* __restrict__ targets,
                                              int* __restrict__ cidx,
                                              int* __restrict__ counts) {
  __shared__ int s1[1024], s2[1024];
  const int tid = threadIdx.x;
  int c[4];
  int n1 = 0, n2 = 0;
#pragma unroll
  for (int j = 0; j < 4; j++) {
    const int t = targets[tid * 4 + j];
    c[j] = (t >= SP1) + (t >= SP2);
    n1 += (c[j] == 1);
    n2 += (c[j] == 2);
  }
  s1[tid] = n1;
  s2[tid] = n2;
  __syncthreads();
  for (int off = 1; off < 1024; off <<= 1) {
    const int a1 = (tid >= off) ? s1[tid - off] : 0;
    const int a2 = (tid >= off) ? s2[tid - off] : 0;
    __syncthreads();
    s1[tid] += a1;
    s2[tid] += a2;
    __syncthreads();
  }
  int e1 = s1[tid] - n1, e2 = s2[tid] - n2;
#pragma unroll
  for (int j = 0; j < 4; j++) {
    if (c[j] == 1) cidx[tid * 4 + j] = e1++;
    else if (c[j] == 2) cidx[tid * 4 + j] = e2++;
    else cidx[tid * 4 + j] = 0;
  }
  if (tid == 1023) {
    counts[0] = s1[1023];
    counts[1] = s2[1023];
    counts[2] = NROWS;
  }
}

// zero both compact-H fp8 buffers (contiguous)
__global__ void zeroHc(uint4* __restrict__ Hc) {
  const size_t n16 = (size_t)2 * NROWS * HH / 16;
  const uint4 z = {0u, 0u, 0u, 0u};
  for (size_t i = (size_t)blockIdx.x * blockDim.x + threadIdx.x; i < n16;
       i += (size_t)gridDim.x * blockDim.x)
    Hc[i] = z;
}

// gather fp8 H rows into per-cluster compact matrices (1 wave per row)
__global__ __launch_bounds__(256) void gatherK(const unsigned char* __restrict__ Hf,
                                               const int* __restrict__ targets,
                                               const int* __restrict__ cidx,
                                               unsigned char* __restrict__ Hc1,
                                               unsigned char* __restrict__ Hc2) {
  const int row = blockIdx.x * 4 + (threadIdx.x >> 6);
  const int lane = threadIdx.x & 63;
  const int t = targets[row];
  const int cl = (t >= SP1) + (t >= SP2);
  if (cl == 0) return;
  unsigned char* dst = (cl == 1 ? Hc1 : Hc2) + (size_t)cidx[row] * HH;
  const unsigned char* src = Hf + (size_t)row * HH;
  *(uint4*)(dst + lane * 16) = *(const uint4*)(src + lane * 16);
}

// ---- fused MX-fp8 GEMM (all 3 segments) + sum-exp epilogue ----
// One dispatch: blocks [0,NB2)=tail2, [NB2,NB2+NB1)=tail1, rest=head.
// Within a segment colTile is fastest (trailing early-exits, XCD balance).
// 512 threads (8 waves = 4M x 2N, wave 64x128 -> 0.75 KB LDS-read/MFMA vs
// 1.0 at 64x64); BK=128, A+B LDS-staged (gload_lds, 144-B padded rows, dup
// chunk), double-buffer 147456 B -> 1 block/CU (8 waves), vmcnt(9), unroll 1.
// acc 128 VGPR + 8 held B frags (64) + streamed A frag; cap 256 via (512,2).
__global__ __launch_bounds__(512, 2) void gemm_fused(
    const unsigned char* __restrict__ Hf, const unsigned char* __restrict__ Hc1,
    const unsigned char* __restrict__ Hc2, const unsigned char* __restrict__ Wf,
    const float* __restrict__ biasr, float* __restrict__ ph,
    float* __restrict__ pt1, float* __restrict__ pt2,
    const int* __restrict__ counts) {
  const int bid = blockIdx.x;
  const unsigned char* Ab;
  float* partials;
  int CT, colbase, col_limit, b, Mc;
  if (bid < NB2) {
    b = bid; CT = CT_T2; colbase = CB_T2; col_limit = CL_T2;
    Ab = Hc2; partials = pt2; Mc = counts[1];
  } else if (bid < NB2 + NB1) {
    b = bid - NB2; CT = CT_T1; colbase = CB_T1; col_limit = CL_T1;
    Ab = Hc1; partials = pt1; Mc = counts[0];
  } else {
    b = bid - NB2 - NB1; CT = CT_HEAD; colbase = 0; col_limit = CL_HEAD;
    Ab = Hf; partials = ph; Mc = NROWS;
  }
  const int rowTile = b / CT;
  const int colTile = b - rowTile * CT;
  if (rowTile * BM >= Mc) return;

  __shared__ __align__(16) unsigned char lds[2 * SLOT_B];  // 147456 B

  const int tid = threadIdx.x;
  const int w = tid >> 6, lane = tid & 63;
  const int wr = w >> 1, wc = w & 1;   // 4M x 2N
  const int fr = lane & 15, fq = lane >> 4;
  const unsigned char* Ag = Ab + (size_t)rowTile * BM * HH;
  const unsigned char* Bg = Wf + (size_t)(colbase + colTile * BN) * HH;

  // staging: chunk c=i*512+tid (16B) -> dest byte c*16.
  // rows 0..255 = A, 256..511 = B; per row 9 chunks (j==8 dups j=0 into pad).
  // i=0..3 all A, i=4 split (tid<256 A), i=5..8 all B.
  int srcOff[LPT];
  const unsigned char* baseI4;
  {
#pragma unroll
    for (int i = 0; i < LPT; i++) {
      const int c = i * 512 + tid;
      const int gr = c / 9, j = c - gr * 9;
      const int jb = (j < 8) ? j * 16 : 0;
      const int r = (gr < BM) ? gr : gr - BM;
      srcOff[i] = r * HH + jb;
    }
    baseI4 = (tid < 256) ? Ag : Bg;
  }

  // fragment read offsets (bytes within slot); hi half at +16 (contiguous)
  int offA[4], offB[8];
#pragma unroll
  for (int mi = 0; mi < 4; mi++) {
    const int R = wr * 64 + mi * 16 + fr;
    offA[mi] = R * ROWB + fq * 32;
  }
#pragma unroll
  for (int ni = 0; ni < 8; ni++) {
    const int R = wc * 128 + ni * 16 + fr;
    offB[ni] = A_SLOT_B + R * ROWB + fq * 32;
  }

  f32x4 acc[4][8];
#pragma unroll
  for (int i = 0; i < 4; i++)
#pragma unroll
    for (int j = 0; j < 8; j++) acc[i][j] = (f32x4){0.f, 0.f, 0.f, 0.f};

  auto STAGE = [&](int t) {
    unsigned char* base = lds + (t & 1) * SLOT_B;
    const int k0 = t * BK;
#pragma unroll
    for (int i = 0; i < LPT; i++) {
      const unsigned char* src = (i < 4) ? Ag : (i == 4 ? baseI4 : Bg);
      gload16(src + (size_t)srcOff[i] + k0, base + (i * 512 + tid) * 16);
    }
  };

  STAGE(0);

#pragma unroll 1
  for (int t = 0; t < NKT; ++t) {
    if (t + 1 < NKT) {
      STAGE(t + 1);
      asm volatile("s_waitcnt vmcnt(9)" ::: "memory");
    } else {
      asm volatile("s_waitcnt vmcnt(0)" ::: "memory");
    }
    __builtin_amdgcn_s_barrier();

    const unsigned char* sl = lds + (t & 1) * SLOT_B;
    // hold all 8 B fragments (64 VGPR)
    i32x8 b8[8];
#pragma unroll
    for (int ni = 0; ni < 8; ni++) {
      i32x4 lo = *(const i32x4*)(sl + offB[ni]);
      i32x4 hi = *(const i32x4*)(sl + offB[ni] + 16);
      b8[ni] = __builtin_shufflevector(lo, hi, 0, 1, 2, 3, 4, 5, 6, 7);
    }
    __builtin_amdgcn_s_setprio(1);
#pragma unroll
    for (int mi = 0; mi < 4; mi++) {
      i32x4 lo = *(const i32x4*)(sl + offA[mi]);
      i32x4 hi = *(const i32x4*)(sl + offA[mi] + 16);
      i32x8 a8 = __builtin_shufflevector(lo, hi, 0, 1, 2, 3, 4, 5, 6, 7);
#pragma unroll
      for (int ni = 0; ni < 8; ni++)
        acc[mi][ni] = __builtin_amdgcn_mfma_scale_f32_16x16x128_f8f6f4(
            a8, b8[ni], acc[mi][ni], 0, 0, 0, UNIT_SCALE, 0, UNIT_SCALE);
    }
    __builtin_amdgcn_s_setprio(0);
    __builtin_amdgcn_s_barrier();
  }

  // ---- epilogue: per-(row, 128-col wave chunk) sum of exp(logit/4096+bias) ----
  const int colw = colTile * BN + wc * 128;
  float biasv[8];
#pragma unroll
  for (int ni = 0; ni < 8; ni++) {
    const int gcol = colbase + colw + ni * 16 + fr;
    biasv[ni] = (gcol < col_limit) ? biasr[gcol] : -1e30f;
  }
  const int chunk = colTile * 2 + wc;
  const int pstride = CT * 2;

#pragma unroll
  for (int mi = 0; mi < 4; mi++) {
    const int rowg = rowTile * BM + wr * 64 + mi * 16 + fq * 4;
#pragma unroll
    for (int r = 0; r < 4; r++) {
      float p = 0.f;
#pragma unroll
      for (int ni = 0; ni < 8; ni++)
        p += __expf(acc[mi][ni][r] * INVSCALE + biasv[ni]);
#pragma unroll
      for (int m = 1; m < 16; m <<= 1) p += __shfl_xor(p, m);
      if (fr == 0) partials[(size_t)(rowg + r) * pstride + chunk] = p;
    }
  }
}

// ---- per-row: combine chunk partials, selected logits in fp32, loss ----
__global__ __launch_bounds__(256) void rowloss(
    const float* __restrict__ ph, const float* __restrict__ pt1,
    const float* __restrict__ pt2, const int* __restrict__ cidx,
    const float* __restrict__ hiddens, const float* __restrict__ weight,
    const float* __restrict__ bias, const float* __restrict__ tails,
    const float* __restrict__ tail_bias, const int* __restrict__ targets,
    float* __restrict__ losses) {
  const int row = blockIdx.x * 4 + (threadIdx.x >> 6);
  const int lane = threadIdx.x & 63;
  const int t = targets[row];
  const int cl = (t >= SP1) + (t >= SP2);

  float s0 = (lane < PH_STRIDE) ? ph[(size_t)row * PH_STRIDE + lane] : 0.f;
  float st = 0.f;
  if (cl == 1) {
    const float* P = pt1 + (size_t)cidx[row] * PT1_STRIDE;
    for (int c = lane; c < PT1_STRIDE; c += 64) st += P[c];
  } else if (cl == 2) {
    const float* P = pt2 + (size_t)cidx[row] * PT2_STRIDE;
    for (int c = lane; c < PT2_STRIDE; c += 64) st += P[c];
  }
#pragma unroll
  for (int m = 1; m < 64; m <<= 1) {
    s0 += __shfl_xor(s0, m);
    st += __shfl_xor(st, m);
  }

  const float* hv = hiddens + (size_t)row * HH;
  const float* w1;
  float b1;
  if (cl == 0) {
    w1 = weight + (size_t)t * HH;
    b1 = bias[t];
  } else if (cl == 1) {
    w1 = tails + HH;  // head col 4001 <-> tail_vectors[1]
    b1 = tail_bias[1];
  } else {
    w1 = tails;       // head col 4000 <-> tail_vectors[0]
    b1 = tail_bias[0];
  }
  float d1 = 0.f, d2 = 0.f;
  for (int i = lane; i < HH; i += 64) d1 += hv[i] * w1[i];
  if (cl > 0) {
    const float* w2 = weight + (size_t)t * HH;
    for (int i = lane; i < HH; i += 64) d2 += hv[i] * w2[i];
  }
#pragma unroll
  for (int m = 1; m < 64; m <<= 1) {
    d1 += __shfl_xor(d1, m);
    d2 += __shfl_xor(d2, m);
  }
  if (lane == 0) {
    float loss = logf(s0) - (d1 + b1);
    if (cl > 0) loss += logf(st) - (d2 + bias[t]);
    losses[row] = loss;
  }
}

__global__ void meanloss(const float* __restrict__ losses, float* __restrict__ out) {
  __shared__ float red[256];
  float s = 0.f;
  for (int i = threadIdx.x; i < NROWS; i += 256) s += losses[i];
  red[threadIdx.x] = s;
  __syncthreads();
  for (int st = 128; st > 0; st >>= 1) {
    if ((int)threadIdx.x < st) red[threadIdx.x] += red[threadIdx.x + st];
    __syncthreads();
  }
  if (threadIdx.x == 0) out[0] = red[0] / (float)NROWS;
}

extern "C" void kernel_launch(void* const* d_in, const int* in_sizes, int n_in,
                              void* d_out, int out_size, void* d_ws, size_t ws_size,
                              hipStream_t stream) {
  const float* weight = (const float*)d_in[0];
  const float* bias = (const float*)d_in[1];
  const float* hiddens = (const float*)d_in[2];
  const float* tails = (const float*)d_in[3];
  const float* tail_bias = (const float*)d_in[4];
  const int* targets = (const int*)d_in[5];
  float* out = (float*)d_out;

  char* ws = (char*)d_ws;
  unsigned char* Wf = (unsigned char*)ws;                      // 50432*1024 = 51,642,368
  unsigned char* Hf = (unsigned char*)(ws + 51642368);         //  4,194,304
  unsigned char* Hc1 = (unsigned char*)(ws + 55836672);        //  4,194,304
  unsigned char* Hc2 = (unsigned char*)(ws + 60030976);        //  4,194,304 (contig w/ Hc1)
  float* ph = (float*)(ws + 64225280);                         //  4096*32*4  =   524,288
  float* pt1 = (float*)(ws + 64749568);                        //  4096*126*4 = 2,064,384
  float* pt2 = (float*)(ws + 66813952);                        //  4096*236*4 = 3,866,624
  float* biasr = (float*)(ws + 70680576);                      //  50432*4    =   201,728
  int* cidx = (int*)(ws + 70882304);                           //  16,384
  int* counts = (int*)(ws + 70898688);                         //  64
  float* losses = (float*)(ws + 70898752);                     //  16,384

  hipLaunchKernelGGL(convW, dim3(2048), dim3(256), 0, stream, weight, tails, Wf);
  hipLaunchKernelGGL(biasK, dim3((VPAD + 255) / 256), dim3(256), 0, stream, bias,
                     tail_bias, biasr);
  hipLaunchKernelGGL(convH, dim3(512), dim3(256), 0, stream, hiddens, Hf);
  hipLaunchKernelGGL(scanK, dim3(1), dim3(1024), 0, stream, targets, cidx, counts);
  hipLaunchKernelGGL(zeroHc, dim3(1024), dim3(256), 0, stream, (uint4*)Hc1);
  hipLaunchKernelGGL(gatherK, dim3(NROWS / 4), dim3(256), 0, stream, Hf, targets, cidx,
                     Hc1, Hc2);
  // fused: tail2 blocks [0,1888), tail1 [1888,2896), head [2896,3152)
  hipLaunchKernelGGL(gemm_fused, dim3(NB2 + NB1 + NBH), dim3(512), 0, stream, Hf, Hc1,
                     Hc2, Wf, biasr, ph, pt1, pt2, counts);
  hipLaunchKernelGGL(rowloss, dim3(NROWS / 4), dim3(256), 0, stream, ph, pt1, pt2, cidx,
                     hiddens, weight, bias, tails, tail_bias, targets, losses);
  hipLaunchKernelGGL(meanloss, dim3(1), dim3(256), 0, stream, losses, out);
}